// Round 2
// baseline (362.262 us; speedup 1.0000x reference)
//
#include <hip/hip_runtime.h>
#include <math.h>

#define N 4096
#define D 256
#define NPOS 32768
#define TEMP 0.07f
#define INVT (1.0f / 0.07f)
#define BIGF 3.0e38f

#define RQ 5.5f                      // quantization range [-RQ, RQ]
#define QS (255.0f / (2.0f * RQ))    // f32 -> u8 scale
#define DEQ (2.0f * RQ / 255.0f)     // u8-units -> f32

#define NT 64                        // 64x64 tiles per dim
#define NTRI (NT * (NT + 1) / 2)     // 2080 triangle blocks
#define KC 16                        // u32 (k4) per D-chunk (=64 dims), 4 chunks
#define LP 68                        // LDS row stride in u32

// workspace layout (floats):
// [0 .. 2*N*64)       pstat[r][c] float2 (pmin, psum), r=row, c=64-col-tile
// [2*N*64 .. +N)      t[r]
// [.. +1]             loss accumulator (float)
// [.. +1]             ticket counter (uint)
// [WS_XQ ..)          xq: N*(D/4) u32 of packed u8 quants
#define WS_PSTAT 0
#define WS_T    (2 * N * NT)
#define WS_ACC  (2 * N * NT + N)
#define WS_CNT  (2 * N * NT + N + 1)
#define WS_XQ   (2 * N * NT + N + 4)   // 16B-aligned

__device__ __forceinline__ void sad_acc(unsigned a, unsigned b, unsigned& c) {
#if __has_builtin(__builtin_amdgcn_sad_u8)
    c = __builtin_amdgcn_sad_u8(a, b, c);
#else
    asm("v_sad_u8 %0, %1, %2, %0" : "+v"(c) : "v"(a), "v"(b));
#endif
}

__device__ __forceinline__ unsigned quant1(float v) {
    const float f = fminf(fmaxf((v + RQ) * QS, 0.0f), 255.0f);
    return (unsigned)__float2uint_rn(f);
}

// quantize f32 -> packed u8 (4/u32), and zero acc/ticket
__global__ __launch_bounds__(256)
void cvt_init_k(const float* __restrict__ x, unsigned* __restrict__ xq,
                float* __restrict__ acc, unsigned* __restrict__ cnt) {
    const int i = blockIdx.x * 256 + threadIdx.x;  // over N*D/4
    const float4 v = ((const float4*)x)[i];
    const unsigned q = quant1(v.x) | (quant1(v.y) << 8) |
                       (quant1(v.z) << 16) | (quant1(v.w) << 24);
    xq[i] = q;
    if (i == 0) { *acc = 0.0f; *cnt = 0u; }
}

// 64x64 tile per block, ONE wave (64 threads), 8x8 micro-tile per lane
// (64 uacc regs).
// R1 POST-MORTEM: __launch_bounds__(64,2) is only a MINIMUM waves/EU — the
// backend's heuristic targeted 4 waves/EU (128 VGPRs) and spilled the
// 64-reg accumulator in the inner loop (WRITE_SIZE 469 MB of scratch,
// 264 us). Grid is 2080 one-wave blocks = ~2 waves/SIMD, grid-limited, so
// occupancy >2 buys nothing. amdgpu_waves_per_eu(2,2) pins the allocator
// to the 256-VGPR budget; pressure is ~170 -> no spill.
__global__ __launch_bounds__(64) __attribute__((amdgpu_waves_per_eu(2, 2)))
void dist_tile_k(const unsigned* __restrict__ xq, float2* __restrict__ pstat) {
    // triangular decode: blockIdx.x -> (bm, bn), bm <= bn
    const int tt = blockIdx.x;
    const int u_ = (NTRI - 1) - tt;
    int r = (int)((sqrtf((float)(8 * u_ + 1)) - 1.0f) * 0.5f);
    while (r * (r + 1) / 2 > u_) --r;
    while ((r + 1) * (r + 2) / 2 <= u_) ++r;
    const int bm = (NT - 1) - r;                      // row tile
    const int bn = (NT - 1) - (u_ - r * (r + 1) / 2); // col tile
    const bool diag = (bm == bn);

    const int lane = threadIdx.x;   // 0..63
    const int tx = lane & 7;        // col group: cols tx*8 .. +7
    const int ty = lane >> 3;       // row group: rows ty*8 .. +7

    __shared__ unsigned As[KC][LP];    // 4.35 KB
    __shared__ unsigned Bs[KC][LP];    // 4.35 KB

    unsigned uacc[8][8];  // [i][j]: row ty*8+i, col tx*8+j
#pragma unroll
    for (int i = 0; i < 8; ++i)
#pragma unroll
        for (int j = 0; j < 8; ++j) uacc[i][j] = 0u;

    const int rowA0 = bm * 64;
    const int rowB0 = bn * 64;

    // staging: sr = lane>>2 (0..15), su = lane&3; rows sr+16k, k=0..3
    const int sr = lane >> 2;
    const int su = lane & 3;
    const uint4* gA = (const uint4*)xq + (size_t)(rowA0 + sr) * 16 + su;
    const uint4* gB = (const uint4*)xq + (size_t)(rowB0 + sr) * 16 + su;

    // prologue: load chunk 0 into regs
    uint4 la[4], lb[4];
#pragma unroll
    for (int k = 0; k < 4; ++k) {
        la[k] = gA[k * 256];
        lb[k] = gB[k * 256];
    }

#pragma unroll 1
    for (int chk = 0; chk < 4; ++chk) {
        __syncthreads();  // 1-wave: lgkmcnt fence, prev reads done before overwrite
#pragma unroll
        for (int k = 0; k < 4; ++k) {
            As[su * 4 + 0][sr + 16 * k] = la[k].x;
            As[su * 4 + 1][sr + 16 * k] = la[k].y;
            As[su * 4 + 2][sr + 16 * k] = la[k].z;
            As[su * 4 + 3][sr + 16 * k] = la[k].w;
            Bs[su * 4 + 0][sr + 16 * k] = lb[k].x;
            Bs[su * 4 + 1][sr + 16 * k] = lb[k].y;
            Bs[su * 4 + 2][sr + 16 * k] = lb[k].z;
            Bs[su * 4 + 3][sr + 16 * k] = lb[k].w;
        }
        // prefetch next chunk into regs; latency hides under the SAD loop
        uint4 na[4], nb[4];
        if (chk < 3) {
#pragma unroll
            for (int k = 0; k < 4; ++k) {
                na[k] = gA[k * 256 + (chk + 1) * 4];
                nb[k] = gB[k * 256 + (chk + 1) * 4];
            }
        }
        __syncthreads();  // staged data visible before frag reads

#pragma unroll
        for (int k4 = 0; k4 < KC; ++k4) {
            const uint4 a0 = *(const uint4*)&As[k4][ty * 8];
            const uint4 a1 = *(const uint4*)&As[k4][ty * 8 + 4];
            const uint4 b0 = *(const uint4*)&Bs[k4][tx * 8];
            const uint4 b1 = *(const uint4*)&Bs[k4][tx * 8 + 4];
            const unsigned av[8] = {a0.x, a0.y, a0.z, a0.w,
                                    a1.x, a1.y, a1.z, a1.w};
            const unsigned bv[8] = {b0.x, b0.y, b0.z, b0.w,
                                    b1.x, b1.y, b1.z, b1.w};
#pragma unroll
            for (int i = 0; i < 8; ++i)
#pragma unroll
                for (int j = 0; j < 8; ++j)
                    sad_acc(av[i], bv[j], uacc[i][j]);
        }

        if (chk < 3) {
#pragma unroll
            for (int k = 0; k < 4; ++k) { la[k] = na[k]; lb[k] = nb[k]; }
        }
    }

    // dequantize to float
    float acc[8][8];
#pragma unroll
    for (int i = 0; i < 8; ++i)
#pragma unroll
        for (int j = 0; j < 8; ++j)
            acc[i][j] = (float)uacc[i][j] * DEQ;

    // diagonal exclusion: poison self-distance (min skips it, exp -> 0)
    if (diag) {
#pragma unroll
        for (int i = 0; i < 8; ++i)
#pragma unroll
            for (int j = 0; j < 8; ++j)
                if (ty * 8 + i == tx * 8 + j)   // ⇔ ty==tx && i==j
                    acc[i][j] = BIGF;
    }

    // ---- row stats over all 64 cols: reduce across tx (shfl 1,2,4) ----
#pragma unroll
    for (int i = 0; i < 8; ++i) {
        float mn = BIGF;
#pragma unroll
        for (int j = 0; j < 8; ++j) mn = fminf(mn, acc[i][j]);
        mn = fminf(mn, __shfl_xor(mn, 1, 64));
        mn = fminf(mn, __shfl_xor(mn, 2, 64));
        mn = fminf(mn, __shfl_xor(mn, 4, 64));
        float s = 0.0f;
#pragma unroll
        for (int j = 0; j < 8; ++j)
            s += __expf((mn - acc[i][j]) * INVT);
        s += __shfl_xor(s, 1, 64);
        s += __shfl_xor(s, 2, 64);
        s += __shfl_xor(s, 4, 64);
        if (tx == 0)
            pstat[(size_t)(rowA0 + ty * 8 + i) * NT + bn] = make_float2(mn, s);
    }

    // ---- col stats (iff bm < bn): reduce across ty (shfl 8,16,32) ----
    if (!diag) {
#pragma unroll
        for (int j = 0; j < 8; ++j) {
            float mn = BIGF;
#pragma unroll
            for (int i = 0; i < 8; ++i) mn = fminf(mn, acc[i][j]);
            mn = fminf(mn, __shfl_xor(mn, 8, 64));
            mn = fminf(mn, __shfl_xor(mn, 16, 64));
            mn = fminf(mn, __shfl_xor(mn, 32, 64));
            float s = 0.0f;
#pragma unroll
            for (int i = 0; i < 8; ++i)
                s += __expf((mn - acc[i][j]) * INVT);
            s += __shfl_xor(s, 8, 64);
            s += __shfl_xor(s, 16, 64);
            s += __shfl_xor(s, 32, 64);
            if (ty == 0)
                pstat[(size_t)(rowB0 + tx * 8 + j) * NT + bm] =
                    make_float2(mn, s);
        }
    }
}

// One wave per row: coalesced float2 read of the 64 partials, shuffle reduce.
__global__ __launch_bounds__(256)
void row_stats_k(const float2* __restrict__ pstat, float* __restrict__ t) {
    const int r = blockIdx.x * 4 + (threadIdx.x >> 6);
    const int c = threadIdx.x & 63;
    const float2 p = pstat[(size_t)r * NT + c];
    float mn = p.x;
#pragma unroll
    for (int off = 32; off > 0; off >>= 1) mn = fminf(mn, __shfl_xor(mn, off, 64));
    float s = p.y * __expf((mn - p.x) * INVT);
#pragma unroll
    for (int off = 32; off > 0; off >>= 1) s += __shfl_xor(s, off, 64);
    if (c == 0) t[r] = TEMP * __logf(s) - mn;
}

// 1024 blocks x 4 waves x 8 pairs; block-level atomic + ticket: last block
// finalizes the loss.
__global__ __launch_bounds__(256)
void pair_fin_k(const float* __restrict__ x, const int* __restrict__ row,
                const int* __restrict__ col, const float* __restrict__ t,
                float* __restrict__ acc, unsigned* __restrict__ cnt,
                float* __restrict__ out) {
    const int lane = threadIdx.x & 63;
    const int wave = threadIdx.x >> 6;
    const int p0 = (blockIdx.x * 4 + wave) * 8;

    int rp[8], cp[8];
#pragma unroll
    for (int i = 0; i < 8; ++i) { rp[i] = row[p0 + i]; cp[i] = col[p0 + i]; }
    float4 a[8], b[8];
#pragma unroll
    for (int i = 0; i < 8; ++i) {
        a[i] = *(const float4*)&x[(size_t)rp[i] * D + lane * 4];
        b[i] = *(const float4*)&x[(size_t)cp[i] * D + lane * 4];
    }
    float wsum = 0.0f;
#pragma unroll
    for (int i = 0; i < 8; ++i) {
        float d = fabsf(a[i].x - b[i].x) + fabsf(a[i].y - b[i].y) +
                  fabsf(a[i].z - b[i].z) + fabsf(a[i].w - b[i].w);
#pragma unroll
        for (int off = 32; off > 0; off >>= 1) d += __shfl_xor(d, off, 64);
        if (lane == 0) wsum += d + t[rp[i]];
    }

    __shared__ float bs[4];
    if (lane == 0) bs[wave] = wsum;
    __syncthreads();
    if (threadIdx.x == 0) {
        const float tot = bs[0] + bs[1] + bs[2] + bs[3];
        atomicAdd(acc, tot);
        __threadfence();
        const unsigned tk = atomicAdd(cnt, 1u);
        if (tk == (unsigned)(gridDim.x - 1)) {
            const float v = atomicAdd(acc, 0.0f);  // coherent read
            out[0] = v * (1.0f / (float)NPOS);
        }
    }
}

extern "C" void kernel_launch(void* const* d_in, const int* in_sizes, int n_in,
                              void* d_out, int out_size, void* d_ws, size_t ws_size,
                              hipStream_t stream) {
    const float* x = (const float*)d_in[0];
    const int* row = (const int*)d_in[1];
    const int* col = (const int*)d_in[2];
    float* ws = (float*)d_ws;
    float* out = (float*)d_out;
    unsigned* xq = (unsigned*)(ws + WS_XQ);
    float* acc = ws + WS_ACC;
    unsigned* cnt = (unsigned*)(ws + WS_CNT);

    cvt_init_k<<<(N * D / 4) / 256, 256, 0, stream>>>(x, xq, acc, cnt);

    dist_tile_k<<<NTRI, 64, 0, stream>>>(xq, (float2*)(ws + WS_PSTAT));

    row_stats_k<<<N / 4, 256, 0, stream>>>((const float2*)(ws + WS_PSTAT), ws + WS_T);

    pair_fin_k<<<NPOS / 32, 256, 0, stream>>>(x, row, col, ws + WS_T, acc, cnt, out);
}

// Round 3
// 135.605 us; speedup vs baseline: 2.6715x; 2.6715x over previous
//
#include <hip/hip_runtime.h>
#include <math.h>

#define N 4096
#define D 256
#define NPOS 32768
#define TEMP 0.07f
#define INVT (1.0f / 0.07f)
#define BIGF 3.0e38f

#define RQ 5.5f                      // quantization range [-RQ, RQ]
#define QS (255.0f / (2.0f * RQ))    // f32 -> u8 scale
#define DEQ (2.0f * RQ / 255.0f)     // u8-units -> f32

#define NT 64                        // 64x64 tiles per dim
#define NTRI (NT * (NT + 1) / 2)     // 2080 triangle blocks
#define KC 16                        // u32 (k4) per D-chunk (=64 dims), 4 chunks

// workspace layout (floats):
// [0 .. 2*N*64)       pstat[r][c] float2 (pmin, psum), r=row, c=64-col-tile
// [2*N*64 .. +N)      t[r]
// [.. +1]             loss accumulator (float)
// [.. +1]             ticket counter (uint)
// [WS_XQ ..)          xqT: TRANSPOSED quant matrix, xqT[w][r], w=0..63, r=0..4095
#define WS_PSTAT 0
#define WS_T    (2 * N * NT)
#define WS_ACC  (2 * N * NT + N)
#define WS_CNT  (2 * N * NT + N + 1)
#define WS_XQ   (2 * N * NT + N + 4)   // 16B-aligned

__device__ __forceinline__ void sad_acc(unsigned a, unsigned b, unsigned& c) {
#if __has_builtin(__builtin_amdgcn_sad_u8)
    c = __builtin_amdgcn_sad_u8(a, b, c);
#else
    asm("v_sad_u8 %0, %1, %2, %0" : "+v"(c) : "v"(a), "v"(b));
#endif
}

// async global->LDS, 16B per lane. LDS dest = uniform base + lane*16.
__device__ __forceinline__ void g2l16(const unsigned* g, unsigned* l) {
    __builtin_amdgcn_global_load_lds(
        (const __attribute__((address_space(1))) unsigned*)g,
        (__attribute__((address_space(3))) unsigned*)l, 16, 0, 0);
}

__device__ __forceinline__ unsigned quant1(float v) {
    const float f = fminf(fmaxf((v + RQ) * QS, 0.0f), 255.0f);
    return (unsigned)__float2uint_rn(f);
}

// Quantize f32 -> packed u8 and store TRANSPOSED: xqT[w][r] (w=word 0..63,
// r=row). Transposed layout is what lets dist_tile_k stage with
// global_load_lds (linear LDS dest). LDS-transpose: both global sides
// coalesced; [64][65] padding -> conflict-free LDS.
__global__ __launch_bounds__(256)
void cvt_init_k(const float* __restrict__ x, unsigned* __restrict__ xqT,
                float* __restrict__ acc, unsigned* __restrict__ cnt) {
    __shared__ unsigned t[64][65];
    const int r0 = blockIdx.x * 64;     // 64 rows per block
    const int tid = threadIdx.x;
#pragma unroll
    for (int k = 0; k < 16; ++k) {
        const int idx = k * 256 + tid;  // 0..4095 over 64r x 64w
        const int rr = idx >> 6;
        const int w = idx & 63;
        const float4 v = ((const float4*)x)[(size_t)(r0 + rr) * 64 + w];
        t[w][rr] = quant1(v.x) | (quant1(v.y) << 8) |
                   (quant1(v.z) << 16) | (quant1(v.w) << 24);
    }
    __syncthreads();
#pragma unroll
    for (int k = 0; k < 16; ++k) {
        const int idx = k * 256 + tid;
        const int w = idx >> 6;         // wave-uniform per 64-lane group
        const int rr = idx & 63;        // lane -> consecutive r: coalesced
        xqT[(size_t)w * N + r0 + rr] = t[w][rr];
    }
    if (blockIdx.x == 0 && tid == 0) { *acc = 0.0f; *cnt = 0u; }
}

// 64x64 tile per block, ONE wave, 8x8 micro-tile per lane (64 uacc regs).
// R2 POST-MORTEM: the backend insists on a 128-VGPR (4 waves/EU) budget and
// spilled the reg-staged version (474 MB scratch writes). Fix: fit in 128.
// global_load_lds staging removes ALL 64 staging/prefetch VGPRs (global->LDS
// DMA, no reg round-trip). Pressure = 64 acc + 16 frag + addr ~= 95-125.
// Double-buffered LDS [2][16][64] (linear, as gload_lds requires); stage of
// chunk k+1 issues BEFORE the SAD loop on chunk k, so the only waitcnt drain
// (inside __syncthreads) happens ~2000 VALU cycles after issue -> latency
// fully hidden, depth-1 pipeline. Frag reads: 8 distinct b128 addrs at 32B
// stride -> 2-way bank alias -> free (m136).
__global__ __launch_bounds__(64) __attribute__((amdgpu_waves_per_eu(1, 2)))
void dist_tile_k(const unsigned* __restrict__ xqT, float2* __restrict__ pstat) {
    // triangular decode: blockIdx.x -> (bm, bn), bm <= bn
    const int tt = blockIdx.x;
    const int u_ = (NTRI - 1) - tt;
    int r = (int)((sqrtf((float)(8 * u_ + 1)) - 1.0f) * 0.5f);
    while (r * (r + 1) / 2 > u_) --r;
    while ((r + 1) * (r + 2) / 2 <= u_) ++r;
    const int bm = (NT - 1) - r;                      // row tile
    const int bn = (NT - 1) - (u_ - r * (r + 1) / 2); // col tile
    const bool diag = (bm == bn);

    const int lane = threadIdx.x;   // 0..63
    const int tx = lane & 7;        // col group: cols tx*8 .. +7
    const int ty = lane >> 3;       // row group: rows ty*8 .. +7

    __shared__ unsigned As[2][KC][64];    // 4 KB x2
    __shared__ unsigned Bs[2][KC][64];    // 4 KB x2

    unsigned uacc[8][8];  // [i][j]: row ty*8+i, col tx*8+j
#pragma unroll
    for (int i = 0; i < 8; ++i)
#pragma unroll
        for (int j = 0; j < 8; ++j) uacc[i][j] = 0u;

    const int rowA0 = bm * 64;
    const int rowB0 = bn * 64;

    // per-lane global source: lane l covers k4 = q*4 + (l>>4), m = (l&15)*4..+3
    const int lrow = lane >> 4;
    const int lcol = (lane & 15) * 4;
    const unsigned* gA = xqT + (size_t)lrow * N + rowA0 + lcol;
    const unsigned* gB = xqT + (size_t)lrow * N + rowB0 + lcol;

    // prologue: stage chunk 0 -> buf 0
#pragma unroll
    for (int q = 0; q < 4; ++q) {
        g2l16(gA + (size_t)q * 4 * N, &As[0][q * 4][0]);
        g2l16(gB + (size_t)q * 4 * N, &Bs[0][q * 4][0]);
    }
    __syncthreads();   // vmcnt(0): chunk 0 resident

#pragma unroll 1
    for (int chk = 0; chk < 4; ++chk) {
        const int b = chk & 1;
        // issue next chunk's DMA into the other buffer; completes under SAD
        if (chk < 3) {
            const unsigned* pa = gA + (size_t)(chk + 1) * 16 * N;
            const unsigned* pb = gB + (size_t)(chk + 1) * 16 * N;
            unsigned* Ad = &As[b ^ 1][0][0];
            unsigned* Bd = &Bs[b ^ 1][0][0];
#pragma unroll
            for (int q = 0; q < 4; ++q) {
                g2l16(pa + (size_t)q * 4 * N, Ad + q * 256);
                g2l16(pb + (size_t)q * 4 * N, Bd + q * 256);
            }
        }

        const unsigned* Ab = &As[b][0][0];
        const unsigned* Bb = &Bs[b][0][0];
#pragma unroll
        for (int k4 = 0; k4 < KC; ++k4) {
            const uint4 a0 = *(const uint4*)(Ab + k4 * 64 + ty * 8);
            const uint4 a1 = *(const uint4*)(Ab + k4 * 64 + ty * 8 + 4);
            const uint4 b0 = *(const uint4*)(Bb + k4 * 64 + tx * 8);
            const uint4 b1 = *(const uint4*)(Bb + k4 * 64 + tx * 8 + 4);
            const unsigned av[8] = {a0.x, a0.y, a0.z, a0.w,
                                    a1.x, a1.y, a1.z, a1.w};
            const unsigned bv[8] = {b0.x, b0.y, b0.z, b0.w,
                                    b1.x, b1.y, b1.z, b1.w};
#pragma unroll
            for (int i = 0; i < 8; ++i)
#pragma unroll
                for (int j = 0; j < 8; ++j)
                    sad_acc(av[i], bv[j], uacc[i][j]);
        }
        // drains vmcnt (next chunk already landed) + lgkmcnt (frag reads
        // retired) before the buffer we just read gets overwritten.
        __syncthreads();
    }

    // dequantize to float
    float acc[8][8];
#pragma unroll
    for (int i = 0; i < 8; ++i)
#pragma unroll
        for (int j = 0; j < 8; ++j)
            acc[i][j] = (float)uacc[i][j] * DEQ;

    // diagonal exclusion: poison self-distance (min skips it, exp -> 0)
    if (diag) {
#pragma unroll
        for (int i = 0; i < 8; ++i)
#pragma unroll
            for (int j = 0; j < 8; ++j)
                if (ty * 8 + i == tx * 8 + j)   // iff ty==tx && i==j
                    acc[i][j] = BIGF;
    }

    // ---- row stats over all 64 cols: reduce across tx (shfl 1,2,4) ----
#pragma unroll
    for (int i = 0; i < 8; ++i) {
        float mn = BIGF;
#pragma unroll
        for (int j = 0; j < 8; ++j) mn = fminf(mn, acc[i][j]);
        mn = fminf(mn, __shfl_xor(mn, 1, 64));
        mn = fminf(mn, __shfl_xor(mn, 2, 64));
        mn = fminf(mn, __shfl_xor(mn, 4, 64));
        float s = 0.0f;
#pragma unroll
        for (int j = 0; j < 8; ++j)
            s += __expf((mn - acc[i][j]) * INVT);
        s += __shfl_xor(s, 1, 64);
        s += __shfl_xor(s, 2, 64);
        s += __shfl_xor(s, 4, 64);
        if (tx == 0)
            pstat[(size_t)(rowA0 + ty * 8 + i) * NT + bn] = make_float2(mn, s);
    }

    // ---- col stats (iff bm < bn): reduce across ty (shfl 8,16,32) ----
    if (!diag) {
#pragma unroll
        for (int j = 0; j < 8; ++j) {
            float mn = BIGF;
#pragma unroll
            for (int i = 0; i < 8; ++i) mn = fminf(mn, acc[i][j]);
            mn = fminf(mn, __shfl_xor(mn, 8, 64));
            mn = fminf(mn, __shfl_xor(mn, 16, 64));
            mn = fminf(mn, __shfl_xor(mn, 32, 64));
            float s = 0.0f;
#pragma unroll
            for (int i = 0; i < 8; ++i)
                s += __expf((mn - acc[i][j]) * INVT);
            s += __shfl_xor(s, 8, 64);
            s += __shfl_xor(s, 16, 64);
            s += __shfl_xor(s, 32, 64);
            if (ty == 0)
                pstat[(size_t)(rowB0 + tx * 8 + j) * NT + bm] =
                    make_float2(mn, s);
        }
    }
}

// One wave per row: coalesced float2 read of the 64 partials, shuffle reduce.
__global__ __launch_bounds__(256)
void row_stats_k(const float2* __restrict__ pstat, float* __restrict__ t) {
    const int r = blockIdx.x * 4 + (threadIdx.x >> 6);
    const int c = threadIdx.x & 63;
    const float2 p = pstat[(size_t)r * NT + c];
    float mn = p.x;
#pragma unroll
    for (int off = 32; off > 0; off >>= 1) mn = fminf(mn, __shfl_xor(mn, off, 64));
    float s = p.y * __expf((mn - p.x) * INVT);
#pragma unroll
    for (int off = 32; off > 0; off >>= 1) s += __shfl_xor(s, off, 64);
    if (c == 0) t[r] = TEMP * __logf(s) - mn;
}

// 1024 blocks x 4 waves x 8 pairs; block-level atomic + ticket: last block
// finalizes the loss.
__global__ __launch_bounds__(256)
void pair_fin_k(const float* __restrict__ x, const int* __restrict__ row,
                const int* __restrict__ col, const float* __restrict__ t,
                float* __restrict__ acc, unsigned* __restrict__ cnt,
                float* __restrict__ out) {
    const int lane = threadIdx.x & 63;
    const int wave = threadIdx.x >> 6;
    const int p0 = (blockIdx.x * 4 + wave) * 8;

    int rp[8], cp[8];
#pragma unroll
    for (int i = 0; i < 8; ++i) { rp[i] = row[p0 + i]; cp[i] = col[p0 + i]; }
    float4 a[8], b[8];
#pragma unroll
    for (int i = 0; i < 8; ++i) {
        a[i] = *(const float4*)&x[(size_t)rp[i] * D + lane * 4];
        b[i] = *(const float4*)&x[(size_t)cp[i] * D + lane * 4];
    }
    float wsum = 0.0f;
#pragma unroll
    for (int i = 0; i < 8; ++i) {
        float d = fabsf(a[i].x - b[i].x) + fabsf(a[i].y - b[i].y) +
                  fabsf(a[i].z - b[i].z) + fabsf(a[i].w - b[i].w);
#pragma unroll
        for (int off = 32; off > 0; off >>= 1) d += __shfl_xor(d, off, 64);
        if (lane == 0) wsum += d + t[rp[i]];
    }

    __shared__ float bs[4];
    if (lane == 0) bs[wave] = wsum;
    __syncthreads();
    if (threadIdx.x == 0) {
        const float tot = bs[0] + bs[1] + bs[2] + bs[3];
        atomicAdd(acc, tot);
        __threadfence();
        const unsigned tk = atomicAdd(cnt, 1u);
        if (tk == (unsigned)(gridDim.x - 1)) {
            const float v = atomicAdd(acc, 0.0f);  // coherent read
            out[0] = v * (1.0f / (float)NPOS);
        }
    }
}

extern "C" void kernel_launch(void* const* d_in, const int* in_sizes, int n_in,
                              void* d_out, int out_size, void* d_ws, size_t ws_size,
                              hipStream_t stream) {
    const float* x = (const float*)d_in[0];
    const int* row = (const int*)d_in[1];
    const int* col = (const int*)d_in[2];
    float* ws = (float*)d_ws;
    float* out = (float*)d_out;
    unsigned* xqT = (unsigned*)(ws + WS_XQ);
    float* acc = ws + WS_ACC;
    unsigned* cnt = (unsigned*)(ws + WS_CNT);

    cvt_init_k<<<N / 64, 256, 0, stream>>>(x, xqT, acc, cnt);

    dist_tile_k<<<NTRI, 64, 0, stream>>>(xqT, (float2*)(ws + WS_PSTAT));

    row_stats_k<<<N / 4, 256, 0, stream>>>((const float2*)(ws + WS_PSTAT), ws + WS_T);

    pair_fin_k<<<NPOS / 32, 256, 0, stream>>>(x, row, col, ws + WS_T, acc, cnt, out);
}

// Round 4
// 134.541 us; speedup vs baseline: 2.6926x; 1.0079x over previous
//
#include <hip/hip_runtime.h>
#include <math.h>

#define N 4096
#define D 256
#define NPOS 32768
#define TEMP 0.07f
#define INVT (1.0f / 0.07f)
#define BIGF 3.0e38f

#define RQ 5.5f                      // quantization range [-RQ, RQ]
#define QS (255.0f / (2.0f * RQ))    // f32 -> u8 scale
#define DEQ (2.0f * RQ / 255.0f)     // u8-units -> f32

#define NT 64                        // 64x64 tiles per dim
#define NTRI (NT * (NT + 1) / 2)     // 2080 triangle blocks
#define KC 16                        // u32 (k4) per D-chunk (=64 dims), 4 chunks

// workspace layout (floats):
// [0 .. 2*N*64)       pstat[r][c] float2 (pmin, psum), r=row, c=64-col-tile
// [2*N*64 .. +N)      t[r]
// [.. +1]             loss accumulator (float)
// [.. +1]             ticket counter (uint)
// [WS_XQ ..)          xqT: TRANSPOSED quant matrix, xqT[w][r], w=0..63, r=0..4095
#define WS_PSTAT 0
#define WS_T    (2 * N * NT)
#define WS_ACC  (2 * N * NT + N)
#define WS_CNT  (2 * N * NT + N + 1)
#define WS_XQ   (2 * N * NT + N + 4)   // 16B-aligned

__device__ __forceinline__ void sad_acc(unsigned a, unsigned b, unsigned& c) {
#if __has_builtin(__builtin_amdgcn_sad_u8)
    c = __builtin_amdgcn_sad_u8(a, b, c);
#else
    asm("v_sad_u8 %0, %1, %2, %0" : "+v"(c) : "v"(a), "v"(b));
#endif
}

// async global->LDS, 16B per lane. LDS dest = uniform base + lane*16.
__device__ __forceinline__ void g2l16(const unsigned* g, unsigned* l) {
    __builtin_amdgcn_global_load_lds(
        (const __attribute__((address_space(1))) unsigned*)g,
        (__attribute__((address_space(3))) unsigned*)l, 16, 0, 0);
}

__device__ __forceinline__ unsigned quant1(float v) {
    const float f = fminf(fmaxf((v + RQ) * QS, 0.0f), 255.0f);
    return (unsigned)__float2uint_rn(f);
}

// Quantize f32 -> packed u8 and store TRANSPOSED: xqT[w][r] (w=word 0..63,
// r=row). Transposed layout is what lets dist_tile_k stage with
// global_load_lds (linear LDS dest). LDS-transpose: both global sides
// coalesced; [64][65] padding -> conflict-free LDS.
__global__ __launch_bounds__(256)
void cvt_init_k(const float* __restrict__ x, unsigned* __restrict__ xqT,
                float* __restrict__ acc, unsigned* __restrict__ cnt) {
    __shared__ unsigned t[64][65];
    const int r0 = blockIdx.x * 64;     // 64 rows per block
    const int tid = threadIdx.x;
#pragma unroll
    for (int k = 0; k < 16; ++k) {
        const int idx = k * 256 + tid;  // 0..4095 over 64r x 64w
        const int rr = idx >> 6;
        const int w = idx & 63;
        const float4 v = ((const float4*)x)[(size_t)(r0 + rr) * 64 + w];
        t[w][rr] = quant1(v.x) | (quant1(v.y) << 8) |
                   (quant1(v.z) << 16) | (quant1(v.w) << 24);
    }
    __syncthreads();
#pragma unroll
    for (int k = 0; k < 16; ++k) {
        const int idx = k * 256 + tid;
        const int w = idx >> 6;         // wave-uniform per 64-lane group
        const int rr = idx & 63;        // lane -> consecutive r: coalesced
        xqT[(size_t)w * N + r0 + rr] = t[w][rr];
    }
    if (blockIdx.x == 0 && tid == 0) { *acc = 0.0f; *cnt = 0u; }
}

// 64x64 tile per block, ONE wave, 8x8 micro-tile per lane (64 uacc regs).
// R3 POST-MORTEM: spill fixed (VGPR=88) but VALUBusy=38% — the allocator
// kept only ONE frag set, so each k4 iteration serializes ds_read latency
// (~120 cyc) with SAD issue (~128 cyc), and at ~1 wave/SIMD there's no TLP
// to cover it. Fix: SOURCE-LEVEL software pipeline — double-buffer the 4
// frag regs, reading k4+1 during k4's SADs. +16 VGPR -> ~112, still under
// the 128 budget, no spill. Chunk order: frag-read(k4=0) -> next-chunk DMA
// issue -> SAD loop, so prologue read latency hides under DMA addr setup.
__global__ __launch_bounds__(64) __attribute__((amdgpu_waves_per_eu(1, 2)))
void dist_tile_k(const unsigned* __restrict__ xqT, float2* __restrict__ pstat) {
    // triangular decode: blockIdx.x -> (bm, bn), bm <= bn
    const int tt = blockIdx.x;
    const int u_ = (NTRI - 1) - tt;
    int r = (int)((sqrtf((float)(8 * u_ + 1)) - 1.0f) * 0.5f);
    while (r * (r + 1) / 2 > u_) --r;
    while ((r + 1) * (r + 2) / 2 <= u_) ++r;
    const int bm = (NT - 1) - r;                      // row tile
    const int bn = (NT - 1) - (u_ - r * (r + 1) / 2); // col tile
    const bool diag = (bm == bn);

    const int lane = threadIdx.x;   // 0..63
    const int tx = lane & 7;        // col group: cols tx*8 .. +7
    const int ty = lane >> 3;       // row group: rows ty*8 .. +7

    __shared__ unsigned As[2][KC][64];    // 4 KB x2
    __shared__ unsigned Bs[2][KC][64];    // 4 KB x2

    unsigned uacc[8][8];  // [i][j]: row ty*8+i, col tx*8+j
#pragma unroll
    for (int i = 0; i < 8; ++i)
#pragma unroll
        for (int j = 0; j < 8; ++j) uacc[i][j] = 0u;

    const int rowA0 = bm * 64;
    const int rowB0 = bn * 64;

    // per-lane global source: lane l covers k4 = q*4 + (l>>4), m = (l&15)*4..+3
    const int lrow = lane >> 4;
    const int lcol = (lane & 15) * 4;
    const unsigned* gA = xqT + (size_t)lrow * N + rowA0 + lcol;
    const unsigned* gB = xqT + (size_t)lrow * N + rowB0 + lcol;

    // prologue: stage chunk 0 -> buf 0
#pragma unroll
    for (int q = 0; q < 4; ++q) {
        g2l16(gA + (size_t)q * 4 * N, &As[0][q * 4][0]);
        g2l16(gB + (size_t)q * 4 * N, &Bs[0][q * 4][0]);
    }
    __syncthreads();   // vmcnt(0): chunk 0 resident

#pragma unroll 1
    for (int chk = 0; chk < 4; ++chk) {
        const int b = chk & 1;
        const unsigned* Ab = &As[b][0][0];
        const unsigned* Bb = &Bs[b][0][0];

        // frag reads for k4=0 first: their latency hides under DMA addr setup
        uint4 a0 = *(const uint4*)(Ab + ty * 8);
        uint4 a1 = *(const uint4*)(Ab + ty * 8 + 4);
        uint4 b0 = *(const uint4*)(Bb + tx * 8);
        uint4 b1 = *(const uint4*)(Bb + tx * 8 + 4);

        // issue next chunk's DMA into the other buffer; completes under SAD
        if (chk < 3) {
            const unsigned* pa = gA + (size_t)(chk + 1) * 16 * N;
            const unsigned* pb = gB + (size_t)(chk + 1) * 16 * N;
            unsigned* Ad = &As[b ^ 1][0][0];
            unsigned* Bd = &Bs[b ^ 1][0][0];
#pragma unroll
            for (int q = 0; q < 4; ++q) {
                g2l16(pa + (size_t)q * 4 * N, Ad + q * 256);
                g2l16(pb + (size_t)q * 4 * N, Bd + q * 256);
            }
        }

        // software-pipelined SAD loop: reads for k4+1 in flight during k4's SADs
#pragma unroll
        for (int k4 = 0; k4 < KC; ++k4) {
            uint4 na0, na1, nb0, nb1;
            if (k4 + 1 < KC) {
                na0 = *(const uint4*)(Ab + (k4 + 1) * 64 + ty * 8);
                na1 = *(const uint4*)(Ab + (k4 + 1) * 64 + ty * 8 + 4);
                nb0 = *(const uint4*)(Bb + (k4 + 1) * 64 + tx * 8);
                nb1 = *(const uint4*)(Bb + (k4 + 1) * 64 + tx * 8 + 4);
            }
            const unsigned av[8] = {a0.x, a0.y, a0.z, a0.w,
                                    a1.x, a1.y, a1.z, a1.w};
            const unsigned bv[8] = {b0.x, b0.y, b0.z, b0.w,
                                    b1.x, b1.y, b1.z, b1.w};
#pragma unroll
            for (int i = 0; i < 8; ++i)
#pragma unroll
                for (int j = 0; j < 8; ++j)
                    sad_acc(av[i], bv[j], uacc[i][j]);
            if (k4 + 1 < KC) { a0 = na0; a1 = na1; b0 = nb0; b1 = nb1; }
        }
        // drains vmcnt (next chunk landed long ago) + lgkmcnt before the
        // buffer we just read gets overwritten.
        __syncthreads();
    }

    // dequantize to float
    float acc[8][8];
#pragma unroll
    for (int i = 0; i < 8; ++i)
#pragma unroll
        for (int j = 0; j < 8; ++j)
            acc[i][j] = (float)uacc[i][j] * DEQ;

    // diagonal exclusion: poison self-distance (min skips it, exp -> 0)
    if (diag) {
#pragma unroll
        for (int i = 0; i < 8; ++i)
#pragma unroll
            for (int j = 0; j < 8; ++j)
                if (ty * 8 + i == tx * 8 + j)   // iff ty==tx && i==j
                    acc[i][j] = BIGF;
    }

    // ---- row stats over all 64 cols: reduce across tx (shfl 1,2,4) ----
#pragma unroll
    for (int i = 0; i < 8; ++i) {
        float mn = BIGF;
#pragma unroll
        for (int j = 0; j < 8; ++j) mn = fminf(mn, acc[i][j]);
        mn = fminf(mn, __shfl_xor(mn, 1, 64));
        mn = fminf(mn, __shfl_xor(mn, 2, 64));
        mn = fminf(mn, __shfl_xor(mn, 4, 64));
        float s = 0.0f;
#pragma unroll
        for (int j = 0; j < 8; ++j)
            s += __expf((mn - acc[i][j]) * INVT);
        s += __shfl_xor(s, 1, 64);
        s += __shfl_xor(s, 2, 64);
        s += __shfl_xor(s, 4, 64);
        if (tx == 0)
            pstat[(size_t)(rowA0 + ty * 8 + i) * NT + bn] = make_float2(mn, s);
    }

    // ---- col stats (iff bm < bn): reduce across ty (shfl 8,16,32) ----
    if (!diag) {
#pragma unroll
        for (int j = 0; j < 8; ++j) {
            float mn = BIGF;
#pragma unroll
            for (int i = 0; i < 8; ++i) mn = fminf(mn, acc[i][j]);
            mn = fminf(mn, __shfl_xor(mn, 8, 64));
            mn = fminf(mn, __shfl_xor(mn, 16, 64));
            mn = fminf(mn, __shfl_xor(mn, 32, 64));
            float s = 0.0f;
#pragma unroll
            for (int i = 0; i < 8; ++i)
                s += __expf((mn - acc[i][j]) * INVT);
            s += __shfl_xor(s, 8, 64);
            s += __shfl_xor(s, 16, 64);
            s += __shfl_xor(s, 32, 64);
            if (ty == 0)
                pstat[(size_t)(rowB0 + tx * 8 + j) * NT + bm] =
                    make_float2(mn, s);
        }
    }
}

// One wave per row: coalesced float2 read of the 64 partials, shuffle reduce.
__global__ __launch_bounds__(256)
void row_stats_k(const float2* __restrict__ pstat, float* __restrict__ t) {
    const int r = blockIdx.x * 4 + (threadIdx.x >> 6);
    const int c = threadIdx.x & 63;
    const float2 p = pstat[(size_t)r * NT + c];
    float mn = p.x;
#pragma unroll
    for (int off = 32; off > 0; off >>= 1) mn = fminf(mn, __shfl_xor(mn, off, 64));
    float s = p.y * __expf((mn - p.x) * INVT);
#pragma unroll
    for (int off = 32; off > 0; off >>= 1) s += __shfl_xor(s, off, 64);
    if (c == 0) t[r] = TEMP * __logf(s) - mn;
}

// 1024 blocks x 4 waves x 8 pairs; block-level atomic + ticket: last block
// finalizes the loss.
__global__ __launch_bounds__(256)
void pair_fin_k(const float* __restrict__ x, const int* __restrict__ row,
                const int* __restrict__ col, const float* __restrict__ t,
                float* __restrict__ acc, unsigned* __restrict__ cnt,
                float* __restrict__ out) {
    const int lane = threadIdx.x & 63;
    const int wave = threadIdx.x >> 6;
    const int p0 = (blockIdx.x * 4 + wave) * 8;

    int rp[8], cp[8];
#pragma unroll
    for (int i = 0; i < 8; ++i) { rp[i] = row[p0 + i]; cp[i] = col[p0 + i]; }
    float4 a[8], b[8];
#pragma unroll
    for (int i = 0; i < 8; ++i) {
        a[i] = *(const float4*)&x[(size_t)rp[i] * D + lane * 4];
        b[i] = *(const float4*)&x[(size_t)cp[i] * D + lane * 4];
    }
    float wsum = 0.0f;
#pragma unroll
    for (int i = 0; i < 8; ++i) {
        float d = fabsf(a[i].x - b[i].x) + fabsf(a[i].y - b[i].y) +
                  fabsf(a[i].z - b[i].z) + fabsf(a[i].w - b[i].w);
#pragma unroll
        for (int off = 32; off > 0; off >>= 1) d += __shfl_xor(d, off, 64);
        if (lane == 0) wsum += d + t[rp[i]];
    }

    __shared__ float bs[4];
    if (lane == 0) bs[wave] = wsum;
    __syncthreads();
    if (threadIdx.x == 0) {
        const float tot = bs[0] + bs[1] + bs[2] + bs[3];
        atomicAdd(acc, tot);
        __threadfence();
        const unsigned tk = atomicAdd(cnt, 1u);
        if (tk == (unsigned)(gridDim.x - 1)) {
            const float v = atomicAdd(acc, 0.0f);  // coherent read
            out[0] = v * (1.0f / (float)NPOS);
        }
    }
}

extern "C" void kernel_launch(void* const* d_in, const int* in_sizes, int n_in,
                              void* d_out, int out_size, void* d_ws, size_t ws_size,
                              hipStream_t stream) {
    const float* x = (const float*)d_in[0];
    const int* row = (const int*)d_in[1];
    const int* col = (const int*)d_in[2];
    float* ws = (float*)d_ws;
    float* out = (float*)d_out;
    unsigned* xqT = (unsigned*)(ws + WS_XQ);
    float* acc = ws + WS_ACC;
    unsigned* cnt = (unsigned*)(ws + WS_CNT);

    cvt_init_k<<<N / 64, 256, 0, stream>>>(x, xqT, acc, cnt);

    dist_tile_k<<<NTRI, 64, 0, stream>>>(xqT, (float2*)(ws + WS_PSTAT));

    row_stats_k<<<N / 4, 256, 0, stream>>>((const float2*)(ws + WS_PSTAT), ws + WS_T);

    pair_fin_k<<<NPOS / 32, 256, 0, stream>>>(x, row, col, ws + WS_T, acc, cnt, out);
}

// Round 5
// 134.133 us; speedup vs baseline: 2.7008x; 1.0030x over previous
//
#include <hip/hip_runtime.h>
#include <math.h>

#define N 4096
#define D 256
#define NPOS 32768
#define TEMP 0.07f
#define INVT (1.0f / 0.07f)
#define BIGF 3.0e38f

#define RQ 5.5f                      // quantization range [-RQ, RQ]
#define QS (255.0f / (2.0f * RQ))    // f32 -> u8 scale
#define DEQ (2.0f * RQ / 255.0f)     // u8-units -> f32

#define NT 64                        // 64x64 tiles per dim
#define NTRI (NT * (NT + 1) / 2)     // 2080 triangle tiles (= 520 blocks x 4 waves)
#define KC 16                        // u32 (k4) per D-chunk (=64 dims), 4 chunks

// workspace layout (floats):
// [0 .. 2*N*64)       pstat[r][c] float2 (pmin, psum), r=row, c=64-col-tile
// [2*N*64 .. +N)      t[r]
// [.. +1]             loss accumulator (float)
// [.. +1]             ticket counter (uint)
// [WS_XQ ..)          xqT: TRANSPOSED quant matrix, xqT[w][r], w=0..63, r=0..4095
#define WS_PSTAT 0
#define WS_T    (2 * N * NT)
#define WS_ACC  (2 * N * NT + N)
#define WS_CNT  (2 * N * NT + N + 1)
#define WS_XQ   (2 * N * NT + N + 4)   // 16B-aligned

__device__ __forceinline__ void sad_acc(unsigned a, unsigned b, unsigned& c) {
#if __has_builtin(__builtin_amdgcn_sad_u8)
    c = __builtin_amdgcn_sad_u8(a, b, c);
#else
    asm("v_sad_u8 %0, %1, %2, %0" : "+v"(c) : "v"(a), "v"(b));
#endif
}

// async global->LDS, 16B per lane. LDS dest = uniform base + lane*16.
__device__ __forceinline__ void g2l16(const unsigned* g, unsigned* l) {
    __builtin_amdgcn_global_load_lds(
        (const __attribute__((address_space(1))) unsigned*)g,
        (__attribute__((address_space(3))) unsigned*)l, 16, 0, 0);
}

__device__ __forceinline__ unsigned quant1(float v) {
    const float f = fminf(fmaxf((v + RQ) * QS, 0.0f), 255.0f);
    return (unsigned)__float2uint_rn(f);
}

// Quantize f32 -> packed u8 and store TRANSPOSED: xqT[w][r] (w=word 0..63,
// r=row). Transposed layout is what lets dist_tile_k stage with
// global_load_lds (linear LDS dest). LDS-transpose: both global sides
// coalesced; [64][65] padding -> conflict-free LDS.
__global__ __launch_bounds__(256)
void cvt_init_k(const float* __restrict__ x, unsigned* __restrict__ xqT,
                float* __restrict__ acc, unsigned* __restrict__ cnt) {
    __shared__ unsigned t[64][65];
    const int r0 = blockIdx.x * 64;     // 64 rows per block
    const int tid = threadIdx.x;
#pragma unroll
    for (int k = 0; k < 16; ++k) {
        const int idx = k * 256 + tid;  // 0..4095 over 64r x 64w
        const int rr = idx >> 6;
        const int w = idx & 63;
        const float4 v = ((const float4*)x)[(size_t)(r0 + rr) * 64 + w];
        t[w][rr] = quant1(v.x) | (quant1(v.y) << 8) |
                   (quant1(v.z) << 16) | (quant1(v.w) << 24);
    }
    __syncthreads();
#pragma unroll
    for (int k = 0; k < 16; ++k) {
        const int idx = k * 256 + tid;
        const int w = idx >> 6;         // wave-uniform per 64-lane group
        const int rr = idx & 63;        // lane -> consecutive r: coalesced
        xqT[(size_t)w * N + r0 + rr] = t[w][rr];
    }
    if (blockIdx.x == 0 && tid == 0) { *acc = 0.0f; *cnt = 0u; }
}

// R4 POST-MORTEM: all structures land at 40-43us; VALUBusy 39% at ~17%
// predicted for 2cyc SADs -> v_sad_u8 is half/quarter-rate; and occupancy
// 0.93 waves/SIMD means the 1-wave blocks ran as TWO SEQUENTIAL passes with
// no TLP to cover the per-k4 lgkmcnt waits. This round:
//  (1) 4 INDEPENDENT waves per block (each its own 64x64 tile + own LDS
//      double-buffer). 520 blocks x 64KB LDS -> exactly 2 blocks/CU ->
//      8 waves/CU = 2/SIMD forced co-residency; one wave's SAD stream
//      covers the other's LDS waits. Barriers identical across waves.
//  (2) manual unroll-by-2 k4 loop with TWO NAMED frag sets (no rotation
//      copies for the allocator to coalesce): reads for k4+1 in flight
//      during k4's 64 SADs. +16 VGPR -> ~110 < 128 budget, no spill.
__global__ __launch_bounds__(256, 2)
void dist_tile_k(const unsigned* __restrict__ xqT, float2* __restrict__ pstat) {
    const int lane = threadIdx.x & 63;
    const int w = threadIdx.x >> 6;      // wave id: owns tile tt
    // triangular decode: tt -> (bm, bn), bm <= bn
    const int tt = blockIdx.x * 4 + w;
    const int u_ = (NTRI - 1) - tt;
    int r = (int)((sqrtf((float)(8 * u_ + 1)) - 1.0f) * 0.5f);
    while (r * (r + 1) / 2 > u_) --r;
    while ((r + 1) * (r + 2) / 2 <= u_) ++r;
    const int bm = (NT - 1) - r;                      // row tile
    const int bn = (NT - 1) - (u_ - r * (r + 1) / 2); // col tile
    const bool diag = (bm == bn);

    const int tx = lane & 7;        // col group: cols tx*8 .. +7
    const int ty = lane >> 3;       // row group: rows ty*8 .. +7

    __shared__ unsigned As[4][2][KC][64];    // 32 KB (per-wave private slabs)
    __shared__ unsigned Bs[4][2][KC][64];    // 32 KB

    unsigned uacc[8][8];  // [i][j]: row ty*8+i, col tx*8+j
#pragma unroll
    for (int i = 0; i < 8; ++i)
#pragma unroll
        for (int j = 0; j < 8; ++j) uacc[i][j] = 0u;

    const int rowA0 = bm * 64;
    const int rowB0 = bn * 64;

    // per-lane global source: lane l covers k4 = q*4 + (l>>4), m = (l&15)*4..+3
    const int lrow = lane >> 4;
    const int lcol = (lane & 15) * 4;
    const unsigned* gA = xqT + (size_t)lrow * N + rowA0 + lcol;
    const unsigned* gB = xqT + (size_t)lrow * N + rowB0 + lcol;

    // prologue: stage chunk 0 -> buf 0
#pragma unroll
    for (int q = 0; q < 4; ++q) {
        g2l16(gA + (size_t)q * 4 * N, &As[w][0][q * 4][0]);
        g2l16(gB + (size_t)q * 4 * N, &Bs[w][0][q * 4][0]);
    }
    __syncthreads();   // vmcnt(0): chunk 0 resident

#pragma unroll 1
    for (int chk = 0; chk < 4; ++chk) {
        const int b = chk & 1;
        const unsigned* Ab = &As[w][b][0][0];
        const unsigned* Bb = &Bs[w][b][0][0];

        // set0 frag reads for k4=0: latency hides under DMA addr setup
        uint4 a0_0 = *(const uint4*)(Ab + ty * 8);
        uint4 a1_0 = *(const uint4*)(Ab + ty * 8 + 4);
        uint4 b0_0 = *(const uint4*)(Bb + tx * 8);
        uint4 b1_0 = *(const uint4*)(Bb + tx * 8 + 4);

        // issue next chunk's DMA into the other buffer; completes under SAD
        if (chk < 3) {
            const unsigned* pa = gA + (size_t)(chk + 1) * 16 * N;
            const unsigned* pb = gB + (size_t)(chk + 1) * 16 * N;
            unsigned* Ad = &As[w][b ^ 1][0][0];
            unsigned* Bd = &Bs[w][b ^ 1][0][0];
#pragma unroll
            for (int q = 0; q < 4; ++q) {
                g2l16(pa + (size_t)q * 4 * N, Ad + q * 256);
                g2l16(pb + (size_t)q * 4 * N, Bd + q * 256);
            }
        }

        // unroll-by-2 software pipeline, two NAMED frag sets (no copies)
#pragma unroll
        for (int k2 = 0; k2 < 8; ++k2) {
            const int k4 = 2 * k2;
            // set1 reads (k4+1) issue before set0's SADs consume lgkmcnt
            const uint4 a0_1 = *(const uint4*)(Ab + (k4 + 1) * 64 + ty * 8);
            const uint4 a1_1 = *(const uint4*)(Ab + (k4 + 1) * 64 + ty * 8 + 4);
            const uint4 b0_1 = *(const uint4*)(Bb + (k4 + 1) * 64 + tx * 8);
            const uint4 b1_1 = *(const uint4*)(Bb + (k4 + 1) * 64 + tx * 8 + 4);
            {
                const unsigned av[8] = {a0_0.x, a0_0.y, a0_0.z, a0_0.w,
                                        a1_0.x, a1_0.y, a1_0.z, a1_0.w};
                const unsigned bv[8] = {b0_0.x, b0_0.y, b0_0.z, b0_0.w,
                                        b1_0.x, b1_0.y, b1_0.z, b1_0.w};
#pragma unroll
                for (int i = 0; i < 8; ++i)
#pragma unroll
                    for (int j = 0; j < 8; ++j)
                        sad_acc(av[i], bv[j], uacc[i][j]);
            }
            if (k2 < 7) {   // set0 reads (k4+2) in flight during set1's SADs
                a0_0 = *(const uint4*)(Ab + (k4 + 2) * 64 + ty * 8);
                a1_0 = *(const uint4*)(Ab + (k4 + 2) * 64 + ty * 8 + 4);
                b0_0 = *(const uint4*)(Bb + (k4 + 2) * 64 + tx * 8);
                b1_0 = *(const uint4*)(Bb + (k4 + 2) * 64 + tx * 8 + 4);
            }
            {
                const unsigned av[8] = {a0_1.x, a0_1.y, a0_1.z, a0_1.w,
                                        a1_1.x, a1_1.y, a1_1.z, a1_1.w};
                const unsigned bv[8] = {b0_1.x, b0_1.y, b0_1.z, b0_1.w,
                                        b1_1.x, b1_1.y, b1_1.z, b1_1.w};
#pragma unroll
                for (int i = 0; i < 8; ++i)
#pragma unroll
                    for (int j = 0; j < 8; ++j)
                        sad_acc(av[i], bv[j], uacc[i][j]);
            }
        }
        // all 4 waves hit the same barrier count; drains this wave's vmcnt
        // (next chunk landed long ago) + lgkmcnt before buffer reuse.
        __syncthreads();
    }

    // dequantize to float
    float acc[8][8];
#pragma unroll
    for (int i = 0; i < 8; ++i)
#pragma unroll
        for (int j = 0; j < 8; ++j)
            acc[i][j] = (float)uacc[i][j] * DEQ;

    // diagonal exclusion: poison self-distance (min skips it, exp -> 0)
    if (diag) {
#pragma unroll
        for (int i = 0; i < 8; ++i)
#pragma unroll
            for (int j = 0; j < 8; ++j)
                if (ty * 8 + i == tx * 8 + j)   // iff ty==tx && i==j
                    acc[i][j] = BIGF;
    }

    // ---- row stats over all 64 cols: reduce across tx (shfl 1,2,4) ----
#pragma unroll
    for (int i = 0; i < 8; ++i) {
        float mn = BIGF;
#pragma unroll
        for (int j = 0; j < 8; ++j) mn = fminf(mn, acc[i][j]);
        mn = fminf(mn, __shfl_xor(mn, 1, 64));
        mn = fminf(mn, __shfl_xor(mn, 2, 64));
        mn = fminf(mn, __shfl_xor(mn, 4, 64));
        float s = 0.0f;
#pragma unroll
        for (int j = 0; j < 8; ++j)
            s += __expf((mn - acc[i][j]) * INVT);
        s += __shfl_xor(s, 1, 64);
        s += __shfl_xor(s, 2, 64);
        s += __shfl_xor(s, 4, 64);
        if (tx == 0)
            pstat[(size_t)(rowA0 + ty * 8 + i) * NT + bn] = make_float2(mn, s);
    }

    // ---- col stats (iff bm < bn): reduce across ty (shfl 8,16,32) ----
    if (!diag) {
#pragma unroll
        for (int j = 0; j < 8; ++j) {
            float mn = BIGF;
#pragma unroll
            for (int i = 0; i < 8; ++i) mn = fminf(mn, acc[i][j]);
            mn = fminf(mn, __shfl_xor(mn, 8, 64));
            mn = fminf(mn, __shfl_xor(mn, 16, 64));
            mn = fminf(mn, __shfl_xor(mn, 32, 64));
            float s = 0.0f;
#pragma unroll
            for (int i = 0; i < 8; ++i)
                s += __expf((mn - acc[i][j]) * INVT);
            s += __shfl_xor(s, 8, 64);
            s += __shfl_xor(s, 16, 64);
            s += __shfl_xor(s, 32, 64);
            if (ty == 0)
                pstat[(size_t)(rowB0 + tx * 8 + j) * NT + bm] =
                    make_float2(mn, s);
        }
    }
}

// One wave per row: coalesced float2 read of the 64 partials, shuffle reduce.
__global__ __launch_bounds__(256)
void row_stats_k(const float2* __restrict__ pstat, float* __restrict__ t) {
    const int r = blockIdx.x * 4 + (threadIdx.x >> 6);
    const int c = threadIdx.x & 63;
    const float2 p = pstat[(size_t)r * NT + c];
    float mn = p.x;
#pragma unroll
    for (int off = 32; off > 0; off >>= 1) mn = fminf(mn, __shfl_xor(mn, off, 64));
    float s = p.y * __expf((mn - p.x) * INVT);
#pragma unroll
    for (int off = 32; off > 0; off >>= 1) s += __shfl_xor(s, off, 64);
    if (c == 0) t[r] = TEMP * __logf(s) - mn;
}

// 1024 blocks x 4 waves x 8 pairs; block-level atomic + ticket: last block
// finalizes the loss.
__global__ __launch_bounds__(256)
void pair_fin_k(const float* __restrict__ x, const int* __restrict__ row,
                const int* __restrict__ col, const float* __restrict__ t,
                float* __restrict__ acc, unsigned* __restrict__ cnt,
                float* __restrict__ out) {
    const int lane = threadIdx.x & 63;
    const int wave = threadIdx.x >> 6;
    const int p0 = (blockIdx.x * 4 + wave) * 8;

    int rp[8], cp[8];
#pragma unroll
    for (int i = 0; i < 8; ++i) { rp[i] = row[p0 + i]; cp[i] = col[p0 + i]; }
    float4 a[8], b[8];
#pragma unroll
    for (int i = 0; i < 8; ++i) {
        a[i] = *(const float4*)&x[(size_t)rp[i] * D + lane * 4];
        b[i] = *(const float4*)&x[(size_t)cp[i] * D + lane * 4];
    }
    float wsum = 0.0f;
#pragma unroll
    for (int i = 0; i < 8; ++i) {
        float d = fabsf(a[i].x - b[i].x) + fabsf(a[i].y - b[i].y) +
                  fabsf(a[i].z - b[i].z) + fabsf(a[i].w - b[i].w);
#pragma unroll
        for (int off = 32; off > 0; off >>= 1) d += __shfl_xor(d, off, 64);
        if (lane == 0) wsum += d + t[rp[i]];
    }

    __shared__ float bs[4];
    if (lane == 0) bs[wave] = wsum;
    __syncthreads();
    if (threadIdx.x == 0) {
        const float tot = bs[0] + bs[1] + bs[2] + bs[3];
        atomicAdd(acc, tot);
        __threadfence();
        const unsigned tk = atomicAdd(cnt, 1u);
        if (tk == (unsigned)(gridDim.x - 1)) {
            const float v = atomicAdd(acc, 0.0f);  // coherent read
            out[0] = v * (1.0f / (float)NPOS);
        }
    }
}

extern "C" void kernel_launch(void* const* d_in, const int* in_sizes, int n_in,
                              void* d_out, int out_size, void* d_ws, size_t ws_size,
                              hipStream_t stream) {
    const float* x = (const float*)d_in[0];
    const int* row = (const int*)d_in[1];
    const int* col = (const int*)d_in[2];
    float* ws = (float*)d_ws;
    float* out = (float*)d_out;
    unsigned* xqT = (unsigned*)(ws + WS_XQ);
    float* acc = ws + WS_ACC;
    unsigned* cnt = (unsigned*)(ws + WS_CNT);

    cvt_init_k<<<N / 64, 256, 0, stream>>>(x, xqT, acc, cnt);

    dist_tile_k<<<NTRI / 4, 256, 0, stream>>>(xqT, (float2*)(ws + WS_PSTAT));

    row_stats_k<<<N / 4, 256, 0, stream>>>((const float2*)(ws + WS_PSTAT), ws + WS_T);

    pair_fin_k<<<NPOS / 32, 256, 0, stream>>>(x, row, col, ws + WS_T, acc, cnt, out);
}